// Round 2
// baseline (701.979 us; speedup 1.0000x reference)
//
#include <hip/hip_runtime.h>
#include <hip/hip_bf16.h>

#define B_ROWS 32768
#define NDEPTH 5

typedef float  f32x4  __attribute__((ext_vector_type(4)));
typedef short  bf16x8 __attribute__((ext_vector_type(8)));

__device__ __forceinline__ unsigned short f2bf(float f) {
    __hip_bfloat16 h = __float2bfloat16(f);   // RNE; compiler emits v_cvt_pk_bf16_f32
    return __builtin_bit_cast(unsigned short, h);
}

// load 8 consecutive f32 and convert to a bf16x8 MFMA fragment
__device__ __forceinline__ bf16x8 cvt8(const float* __restrict__ p) {
    const float4 v0 = *(const float4*)p;
    const float4 v1 = *(const float4*)(p + 4);
    bf16x8 r;
    r[0] = (short)f2bf(v0.x); r[1] = (short)f2bf(v0.y);
    r[2] = (short)f2bf(v0.z); r[3] = (short)f2bf(v0.w);
    r[4] = (short)f2bf(v1.x); r[5] = (short)f2bf(v1.y);
    r[6] = (short)f2bf(v1.z); r[7] = (short)f2bf(v1.w);
    return r;
}

__device__ __forceinline__ float fast_sig(float x) {
    x = fminf(fmaxf(x, -30.f), 30.f);
    return 1.0f / (1.0f + __expf(-x));
}
__device__ __forceinline__ float fast_tanh(float x) {
    x = fminf(fmaxf(x, -15.f), 15.f);
    float e = __expf(2.0f * x);
    return (e - 1.0f) / (e + 1.0f);
}

// ---- all weight transposes (f32 [d][K][N] -> bf16 [d][N][K]) in ONE launch ----
__global__ void wtrans_all(const float* __restrict__ W_cell_h, const float* __restrict__ W_up,
                           const float* __restrict__ W_cell_n, const float* __restrict__ W_inp_h,
                           const float* __restrict__ W_inp_n,
                           unsigned short* __restrict__ wtCellH, unsigned short* __restrict__ wtUp,
                           unsigned short* __restrict__ wtCellN, unsigned short* __restrict__ wtInpH,
                           unsigned short* __restrict__ wtInpN) {
    int t = blockIdx.x;
    const float* in; unsigned short* out; int K, N;
    if (t < 160)       {           in = W_cell_h; out = wtCellH; K = 128; N = 256; }
    else if (t < 320)  { t -= 160; in = W_up;     out = wtUp;    K = 128; N = 256; }
    else if (t < 960)  { t -= 320; in = W_cell_n; out = wtCellN; K = 256; N = 512; }
    else if (t < 1024) { t -= 960; in = W_inp_h;  out = wtInpH;  K = 256; N = 256; }
    else               { t -= 1024; in = W_inp_n; out = wtInpN;  K = 256; N = 512; }
    int tilesPerD = (K / 32) * (N / 32);
    int d = t / tilesPerD, rem = t % tilesPerD;
    int n0 = (rem % (N / 32)) * 32, k0 = (rem / (N / 32)) * 32;
    in  += (size_t)d * K * N;
    out += (size_t)d * K * N;
    __shared__ float tile[32][33];
    int tx = threadIdx.x, ty = threadIdx.y;  // (32,8)
#pragma unroll
    for (int j = 0; j < 32; j += 8)
        tile[ty + j][tx] = in[(size_t)(k0 + ty + j) * N + n0 + tx];
    __syncthreads();
#pragma unroll
    for (int j = 0; j < 32; j += 8)
        out[(size_t)(n0 + ty + j) * K + k0 + tx] = f2bf(tile[tx][ty + j]);
}

// ---- fused HyperRHN: one block = 64 rows x one depth; barrier-free GEMMs ----
__global__ void __launch_bounds__(256, 2)
hyper_rhn_kernel(const float* __restrict__ x,
                 const float* __restrict__ sHyper,
                 const float* __restrict__ sNetwork,
                 const float* __restrict__ b_inp_h,
                 const float* __restrict__ b_cell_h,
                 const float* __restrict__ b_inp_n,
                 const float* __restrict__ b_cell_n,
                 const float* __restrict__ b_up,
                 const unsigned short* __restrict__ wtCellH,  // [5][256][128]
                 const unsigned short* __restrict__ wtUp,     // [5][256][128]
                 const unsigned short* __restrict__ wtCellN,  // [5][512][256]
                 const unsigned short* __restrict__ wtInpH,   // [256][256]
                 const unsigned short* __restrict__ wtInpN,   // [512][256]
                 float* __restrict__ outMain,
                 float* __restrict__ outSH,
                 float* __restrict__ outSN) {
    __shared__ unsigned short sHlds[64 * 128];  // gated hyper state (bf16), XOR-swizzled

    const int l    = blockIdx.y;
    const int r0   = blockIdx.x * 64;
    const int tid  = threadIdx.x;
    const int w    = tid >> 6;     // wave 0..3 (owns col-groups w, w+4, w+8, w+12)
    const int lane = tid & 63;
    const int lr   = lane & 15;
    const int q    = lane >> 4;

    // ========== P1: WsH = sHyper[l] @ W_cell_h[l] (+ x @ W_inp_h at l==0) ==========
    // accH[j][h][rf]: hh col-group w+4j (h=0), tt col-group w+4j+8 (h=1)
    f32x4 accH[2][2][4] = {};
    {
        const float* aBase = sHyper + ((size_t)l * B_ROWS + r0) * 128;
#pragma unroll
        for (int ks = 0; ks < 4; ++ks) {
            bf16x8 af[4];
#pragma unroll
            for (int rf = 0; rf < 4; ++rf)
                af[rf] = cvt8(aBase + (size_t)(rf * 16 + lr) * 128 + ks * 32 + q * 8);
#pragma unroll
            for (int j = 0; j < 2; ++j)
#pragma unroll
                for (int h = 0; h < 2; ++h) {
                    int c = (w + 4 * j + 8 * h) * 16 + lr;
                    bf16x8 bf = *(const bf16x8*)(wtCellH + ((size_t)l * 256 + c) * 128 + ks * 32 + q * 8);
#pragma unroll
                    for (int rf = 0; rf < 4; ++rf)
                        accH[j][h][rf] = __builtin_amdgcn_mfma_f32_16x16x32_bf16(
                            af[rf], bf, accH[j][h][rf], 0, 0, 0);
                }
        }
        if (l == 0) {
            const float* xBase = x + (size_t)r0 * 256;
#pragma unroll
            for (int ks = 0; ks < 8; ++ks) {
                bf16x8 af[4];
#pragma unroll
                for (int rf = 0; rf < 4; ++rf)
                    af[rf] = cvt8(xBase + (size_t)(rf * 16 + lr) * 256 + ks * 32 + q * 8);
#pragma unroll
                for (int j = 0; j < 2; ++j)
#pragma unroll
                    for (int h = 0; h < 2; ++h) {
                        int c = (w + 4 * j + 8 * h) * 16 + lr;
                        bf16x8 bf = *(const bf16x8*)(wtInpH + (size_t)c * 256 + ks * 32 + q * 8);
#pragma unroll
                        for (int rf = 0; rf < 4; ++rf)
                            accH[j][h][rf] = __builtin_amdgcn_mfma_f32_16x16x32_bf16(
                                af[rf], bf, accH[j][h][rf], 0, 0, 0);
                    }
            }
        }
    }

    // ========== P2: hyper highway gate -> outSH (f32) + sHlds (bf16, swizzled) ==========
#pragma unroll
    for (int j = 0; j < 2; ++j) {
        int ch = (w + 4 * j) * 16 + lr;  // 0..127
        float bh = b_cell_h[l * 256 + ch]       + ((l == 0) ? b_inp_h[ch]       : 0.f);
        float bt = b_cell_h[l * 256 + 128 + ch] + ((l == 0) ? b_inp_h[128 + ch] : 0.f);
#pragma unroll
        for (int rf = 0; rf < 4; ++rf)
#pragma unroll
            for (int i = 0; i < 4; ++i) {
                int r = rf * 16 + q * 4 + i;
                size_t gr = (size_t)l * B_ROWS + r0 + r;
                float a  = accH[j][0][rf][i] + bh;
                float g  = accH[j][1][rf][i] + bt;
                float hh = fast_tanh(a);
                float tt = fast_sig(g);
                float sold = sHyper[gr * 128 + ch];
                float sh = hh * tt + sold * (1.0f - tt);
                outSH[gr * 128 + ch] = sh;
                *(unsigned short*)((char*)sHlds + r * 256 + ((ch * 2) ^ ((r & 7) << 4))) = f2bf(sh);
            }
    }
    __syncthreads();

    // ========== per column-chunk: z = sH @ W_up, T = sN @ W_cell_n (+x@W_inp_n), gate ==========
    const float* nBase = sNetwork + ((size_t)l * B_ROWS + r0) * 256;
    const float* xBase = x + (size_t)r0 * 256;
    for (int chunk = 0; chunk < 2; ++chunk) {
        // ---- z for this chunk's 2 col-groups ----
        f32x4 zac[2][4] = {};
#pragma unroll
        for (int ks = 0; ks < 4; ++ks) {
            bf16x8 af[4];
#pragma unroll
            for (int rf = 0; rf < 4; ++rf) {
                int row = rf * 16 + lr;
                af[rf] = *(const bf16x8*)((const char*)sHlds + row * 256 +
                                          (((ks * 64) + q * 16) ^ ((row & 7) << 4)));
            }
#pragma unroll
            for (int jj = 0; jj < 2; ++jj) {
                int cz = (w + 4 * (chunk * 2 + jj)) * 16 + lr;
                bf16x8 bf = *(const bf16x8*)(wtUp + ((size_t)l * 256 + cz) * 128 + ks * 32 + q * 8);
#pragma unroll
                for (int rf = 0; rf < 4; ++rf)
                    zac[jj][rf] = __builtin_amdgcn_mfma_f32_16x16x32_bf16(
                        af[rf], bf, zac[jj][rf], 0, 0, 0);
            }
        }
        // ---- T accumulate for this chunk (hh cols c0, tt cols c0+256) ----
        f32x4 accT[2][2][4] = {};
#pragma unroll
        for (int ks = 0; ks < 8; ++ks) {
            bf16x8 af[4];
#pragma unroll
            for (int rf = 0; rf < 4; ++rf)
                af[rf] = cvt8(nBase + (size_t)(rf * 16 + lr) * 256 + ks * 32 + q * 8);
#pragma unroll
            for (int jj = 0; jj < 2; ++jj)
#pragma unroll
                for (int h = 0; h < 2; ++h) {
                    int c = (w + 4 * (chunk * 2 + jj) + 16 * h) * 16 + lr;
                    bf16x8 bf = *(const bf16x8*)(wtCellN + ((size_t)l * 512 + c) * 256 + ks * 32 + q * 8);
#pragma unroll
                    for (int rf = 0; rf < 4; ++rf)
                        accT[jj][h][rf] = __builtin_amdgcn_mfma_f32_16x16x32_bf16(
                            af[rf], bf, accT[jj][h][rf], 0, 0, 0);
                }
        }
        if (l == 0) {
#pragma unroll
            for (int ks = 0; ks < 8; ++ks) {
                bf16x8 af[4];
#pragma unroll
                for (int rf = 0; rf < 4; ++rf)
                    af[rf] = cvt8(xBase + (size_t)(rf * 16 + lr) * 256 + ks * 32 + q * 8);
#pragma unroll
                for (int jj = 0; jj < 2; ++jj)
#pragma unroll
                    for (int h = 0; h < 2; ++h) {
                        int c = (w + 4 * (chunk * 2 + jj) + 16 * h) * 16 + lr;
                        bf16x8 bf = *(const bf16x8*)(wtInpN + (size_t)c * 256 + ks * 32 + q * 8);
#pragma unroll
                        for (int rf = 0; rf < 4; ++rf)
                            accT[jj][h][rf] = __builtin_amdgcn_mfma_f32_16x16x32_bf16(
                                af[rf], bf, accT[jj][h][rf], 0, 0, 0);
                    }
            }
        }
        // ---- epilogue for this chunk ----
#pragma unroll
        for (int jj = 0; jj < 2; ++jj) {
            int cz = (w + 4 * (chunk * 2 + jj)) * 16 + lr;  // 0..255
            float bz  = b_up[l * 256 + cz];
            float bhn = b_cell_n[l * 512 + cz]       + ((l == 0) ? b_inp_n[cz]       : 0.f);
            float btn = b_cell_n[l * 512 + 256 + cz] + ((l == 0) ? b_inp_n[256 + cz] : 0.f);
#pragma unroll
            for (int rf = 0; rf < 4; ++rf)
#pragma unroll
                for (int i = 0; i < 4; ++i) {
                    int r = rf * 16 + q * 4 + i;
                    size_t gr = (size_t)l * B_ROWS + r0 + r;
                    float zi   = zac[jj][rf][i] + bz;
                    float tpre = zi * (accT[jj][0][rf][i] + bhn);
                    float upre = zi * (accT[jj][1][rf][i] + btn);
                    float hh = fast_tanh(tpre);
                    float tt = fast_sig(upre);
                    float sold = sNetwork[gr * 256 + cz];
                    float sn = hh * tt + sold * (1.0f - tt);
                    outSN[gr * 256 + cz] = sn;
                    if (l == 4) outMain[(size_t)(r0 + r) * 256 + cz] = sn;
                }
        }
    }
}

extern "C" void kernel_launch(void* const* d_in, const int* in_sizes, int n_in,
                              void* d_out, int out_size, void* d_ws, size_t ws_size,
                              hipStream_t stream) {
    const float* x        = (const float*)d_in[0];
    const float* sHyper   = (const float*)d_in[1];
    const float* sNetwork = (const float*)d_in[2];
    const float* W_inp_h  = (const float*)d_in[3];
    const float* b_inp_h  = (const float*)d_in[4];
    const float* W_cell_h = (const float*)d_in[5];
    const float* b_cell_h = (const float*)d_in[6];
    const float* W_inp_n  = (const float*)d_in[7];
    const float* b_inp_n  = (const float*)d_in[8];
    const float* W_cell_n = (const float*)d_in[9];
    const float* b_cell_n = (const float*)d_in[10];
    const float* W_up     = (const float*)d_in[11];
    const float* b_up     = (const float*)d_in[12];

    unsigned short* ws = (unsigned short*)d_ws;
    unsigned short* wtCellH = ws;                  // [5][256][128]
    unsigned short* wtUp    = ws + 163840;         // [5][256][128]
    unsigned short* wtCellN = ws + 327680;         // [5][512][256]
    unsigned short* wtInpH  = ws + 983040;         // [256][256]
    unsigned short* wtInpN  = ws + 1048576;        // [512][256]

    wtrans_all<<<1152, dim3(32, 8), 0, stream>>>(W_cell_h, W_up, W_cell_n, W_inp_h, W_inp_n,
                                                 wtCellH, wtUp, wtCellN, wtInpH, wtInpN);

    float* outMain = (float*)d_out;
    float* outSH = outMain + (size_t)B_ROWS * 256;               // [5][B][128]
    float* outSN = outSH + (size_t)NDEPTH * B_ROWS * 128;        // [5][B][256]

    hyper_rhn_kernel<<<dim3(B_ROWS / 64, NDEPTH), 256, 0, stream>>>(
        x, sHyper, sNetwork,
        b_inp_h, b_cell_h, b_inp_n, b_cell_n, b_up,
        wtCellH, wtUp, wtCellN, wtInpH, wtInpN,
        outMain, outSH, outSN);
}